// Round 3
// baseline (141.356 us; speedup 1.0000x reference)
//
#include <hip/hip_runtime.h>
#include <hip/hip_bf16.h>

typedef __bf16 bf16;
typedef __bf16 bf16x4 __attribute__((ext_vector_type(4)));
typedef __bf16 bf16x8 __attribute__((ext_vector_type(8)));
typedef float f32x4 __attribute__((ext_vector_type(4)));

#define D 256          // embed dim
#define NHEAD 8
#define HD 32          // head dim
#define NB_ 8
#define LQ_ 256
#define LS_ 4096
#define MQ (NB_ * LQ_)   // 2048
#define MS (NB_ * LS_)   // 32768

// softmax scale folded into Q projection: hd^-0.5 * log2(e)
#define QSCALE 0.25500527f

// ---------------------------------------------------------------------------
// prep1: SPb = bf16(source+pe); QPb = bf16(query+qpe); Wb = bf16(weights)
// ---------------------------------------------------------------------------
__global__ __launch_bounds__(256) void prep1(
    const float* __restrict__ source, const float* __restrict__ source_pe,
    const float* __restrict__ query, const float* __restrict__ query_pe,
    const float* __restrict__ w_in, const float* __restrict__ w_out,
    bf16* __restrict__ SPb, bf16* __restrict__ QPb, bf16* __restrict__ Wb)
{
    const int NS4 = MS * D / 4;                  // 2097152
    const int NQ4 = MQ * D / 4;                  // 131072
    const int NW4 = (768 * 256 + 256 * 256) / 4; // 65536
    const int total = NS4 + NQ4 + NW4;
    for (int i = blockIdx.x * 256 + threadIdx.x; i < total; i += gridDim.x * 256) {
        if (i < NS4) {
            const float4 s = ((const float4*)source)[i];
            const float4 p = ((const float4*)source_pe)[i];
            bf16x4 o;
            o[0] = (bf16)(s.x + p.x); o[1] = (bf16)(s.y + p.y);
            o[2] = (bf16)(s.z + p.z); o[3] = (bf16)(s.w + p.w);
            ((bf16x4*)SPb)[i] = o;
        } else if (i < NS4 + NQ4) {
            const int j = i - NS4;
            const float4 s = ((const float4*)query)[j];
            const float4 p = ((const float4*)query_pe)[j];
            bf16x4 o;
            o[0] = (bf16)(s.x + p.x); o[1] = (bf16)(s.y + p.y);
            o[2] = (bf16)(s.z + p.z); o[3] = (bf16)(s.w + p.w);
            ((bf16x4*)QPb)[j] = o;
        } else {
            const int j = i - NS4 - NQ4;
            const float4 v = (j < 49152) ? ((const float4*)w_in)[j]
                                         : ((const float4*)w_out)[j - 49152];
            bf16x4 o;
            o[0] = (bf16)v.x; o[1] = (bf16)v.y; o[2] = (bf16)v.z; o[3] = (bf16)v.w;
            ((bf16x4*)Wb)[j] = o;
        }
    }
}

// prep2: Sb = bf16(source)   (runs after K-GEMM consumed SPb; same buffer)
__global__ __launch_bounds__(256) void prep2(
    const float* __restrict__ source, bf16* __restrict__ Sb)
{
    const int NS4 = MS * D / 4;
    for (int i = blockIdx.x * 256 + threadIdx.x; i < NS4; i += gridDim.x * 256) {
        const float4 s = ((const float4*)source)[i];
        bf16x4 o;
        o[0] = (bf16)s.x; o[1] = (bf16)s.y; o[2] = (bf16)s.z; o[3] = (bf16)s.w;
        ((bf16x4*)Sb)[i] = o;
    }
}

// ---------------------------------------------------------------------------
// bf16 projection GEMM: out[m][n] = (sum_k A[m][k]*W[n][k] + bias[n]) * scale
// tile 128x128, BK=64, 4 waves (2x2).  grid (N/128, M/128).
// ---------------------------------------------------------------------------
__global__ __launch_bounds__(256) void gemm_proj(
    const bf16* __restrict__ A, const bf16* __restrict__ W,
    const float* __restrict__ bias, bf16* __restrict__ out, float scale)
{
    __shared__ bf16 As[128][72];
    __shared__ bf16 Bs[128][72];
    const int tid = threadIdx.x, lane = tid & 63, wid = tid >> 6;
    const int wm = wid >> 1, wn = wid & 1;
    const int nblk = blockIdx.x, mblk = blockIdx.y;

    f32x4 acc[4][4];
    #pragma unroll
    for (int i = 0; i < 4; ++i)
        #pragma unroll
        for (int j = 0; j < 4; ++j) acc[i][j] = (f32x4){0.f, 0.f, 0.f, 0.f};

    const size_t arow0 = (size_t)mblk * 128;
    const int brow0 = nblk * 128;

    for (int kk = 0; kk < 4; ++kk) {
        const int d0 = kk * 64;
        #pragma unroll
        for (int i = 0; i < 4; ++i) {
            const int idx = i * 256 + tid;
            const int r = idx >> 3, c = (idx & 7) * 8;
            *(bf16x8*)&As[r][c] = *(const bf16x8*)&A[(arow0 + r) * D + d0 + c];
            *(bf16x8*)&Bs[r][c] = *(const bf16x8*)&W[(size_t)(brow0 + r) * D + d0 + c];
        }
        __syncthreads();
        #pragma unroll
        for (int h2 = 0; h2 < 2; ++h2) {
            const int ko = h2 * 32 + (lane >> 4) * 8;
            bf16x8 af[4], bfr[4];
            #pragma unroll
            for (int i = 0; i < 4; ++i)
                af[i] = *(const bf16x8*)&As[wm * 64 + i * 16 + (lane & 15)][ko];
            #pragma unroll
            for (int j = 0; j < 4; ++j)
                bfr[j] = *(const bf16x8*)&Bs[wn * 64 + j * 16 + (lane & 15)][ko];
            #pragma unroll
            for (int i = 0; i < 4; ++i)
                #pragma unroll
                for (int j = 0; j < 4; ++j)
                    acc[i][j] = __builtin_amdgcn_mfma_f32_16x16x32_bf16(
                        af[i], bfr[j], acc[i][j], 0, 0, 0);
        }
        __syncthreads();
    }

    #pragma unroll
    for (int i = 0; i < 4; ++i)
        #pragma unroll
        for (int j = 0; j < 4; ++j) {
            const int n_g = brow0 + wn * 64 + j * 16 + (lane & 15);
            const float b = bias[n_g];
            #pragma unroll
            for (int r = 0; r < 4; ++r) {
                const size_t m_g = arow0 + wm * 64 + i * 16 + (lane >> 4) * 4 + r;
                out[m_g * D + n_g] = (bf16)((acc[i][j][r] + b) * scale);
            }
        }
}

// ---------------------------------------------------------------------------
// split-KV flash attention, swapped-QK layout (P is lane-local, no P-LDS).
// grid = 256*S; bid = inner*8 + h (XCD-friendly).  4 waves, 16 q rows/wave.
// kv mapping inside a 64-chunk: tile t row16 (=4g+r) holds
//   kv = 32*(t>>1) + 8*g + 4*(t&1) + r   -> PV A-frag is lane-local.
// ---------------------------------------------------------------------------
template<int S>
__global__ __launch_bounds__(256, 8) void attn_kernel(
    const bf16* __restrict__ Qb, const bf16* __restrict__ Kb,
    const bf16* __restrict__ Vb,
    float* __restrict__ accp, float2* __restrict__ mlp)
{
    __shared__ bf16 Vt[2][32][72];   // V^T chunk, double buffered, XOR-swizzled

    const int tid = threadIdx.x, lane = tid & 63, wid = tid >> 6;
    const int q15 = lane & 15, g = lane >> 4;
    const int bid = blockIdx.x;
    const int h = bid & 7;
    const int inner = bid >> 3;
    const int b = inner / (S * 4);
    const int rem = inner % (S * 4);
    const int split = rem >> 2, qt = rem & 3;

    const int q0 = b * LQ_ + qt * 64 + wid * 16;
    const bf16x8 qf = *(const bf16x8*)&Qb[(size_t)(q0 + q15) * D + h * HD + g * 8];

    const size_t kvbase = (size_t)b * LS_;
    const int kv0 = split * (LS_ / S);
    const f32x4 zero4 = (f32x4){0.f, 0.f, 0.f, 0.f};
    const int rbase = 8 * (q15 >> 2) + (q15 & 3);   // kf row permutation base

    float m_run = -1e30f, l_run = 0.f;
    f32x4 acc0 = zero4, acc1 = zero4;

    const int vrow = tid >> 2, vc = (tid & 3) * 8;

    for (int kc = 0; kc < LS_ / S / 64; ++kc) {
        const int k0 = kv0 + kc * 64;
        const int buf = kc & 1;

        // ---- stage V^T chunk (swizzled: kv' = kv ^ ((d>>3)<<4))
        const bf16x8 vv = *(const bf16x8*)&Vb[(kvbase + k0 + vrow) * D + h * HD + vc];
        #pragma unroll
        for (int j = 0; j < 8; ++j) {
            const int d = vc + j;
            Vt[buf][d][vrow ^ ((d >> 3) << 4)] = vv[j];
        }
        __syncthreads();

        // ---- S^T = K Q^T: lane holds 16 kv scores for q = q0 + q15
        f32x4 s[4];
        #pragma unroll
        for (int t = 0; t < 4; ++t) {
            const int row = 32 * (t >> 1) + 4 * (t & 1) + rbase;
            const bf16x8 kf = *(const bf16x8*)
                &Kb[(kvbase + k0 + row) * D + h * HD + g * 8];
            s[t] = __builtin_amdgcn_mfma_f32_16x16x32_bf16(kf, qf, zero4, 0, 0, 0);
        }

        // ---- per-lane online softmax (2 shfls per reduce)
        float mx = fmaxf(fmaxf(fmaxf(s[0][0], s[0][1]), fmaxf(s[0][2], s[0][3])),
                         fmaxf(fmaxf(s[1][0], s[1][1]), fmaxf(s[1][2], s[1][3])));
        mx = fmaxf(mx, fmaxf(fmaxf(fmaxf(s[2][0], s[2][1]), fmaxf(s[2][2], s[2][3])),
                             fmaxf(fmaxf(s[3][0], s[3][1]), fmaxf(s[3][2], s[3][3]))));
        mx = fmaxf(mx, __shfl_xor(mx, 16));
        mx = fmaxf(mx, __shfl_xor(mx, 32));
        const float mn = fmaxf(m_run, mx);
        const float rs = exp2f(m_run - mn);
        m_run = mn;

        float p[4][4];
        float sum = 0.f;
        #pragma unroll
        for (int t = 0; t < 4; ++t)
            #pragma unroll
            for (int r = 0; r < 4; ++r) {
                p[t][r] = exp2f(s[t][r] - mn);
                sum += p[t][r];
            }
        sum += __shfl_xor(sum, 16);
        sum += __shfl_xor(sum, 32);
        l_run = l_run * rs + sum;

        // ---- rescale acc rows (row r belongs to q' = g*4 + r)
        #pragma unroll
        for (int r = 0; r < 4; ++r) {
            const float rsr = __shfl(rs, (lane & 48) | (g * 4 + r));
            acc0[r] *= rsr;
            acc1[r] *= rsr;
        }

        // ---- P fragments are lane-local thanks to the kv mapping
        bf16x8 pa0, pa1;
        #pragma unroll
        for (int r = 0; r < 4; ++r) {
            pa0[r]     = (bf16)p[0][r];
            pa0[4 + r] = (bf16)p[1][r];
            pa1[r]     = (bf16)p[2][r];
            pa1[4 + r] = (bf16)p[3][r];
        }

        // ---- O += P V
        #pragma unroll
        for (int dt = 0; dt < 2; ++dt) {
            const int d = dt * 16 + q15;
            const int sw = (d >> 3) << 4;
            const bf16x8 vb0 = *(const bf16x8*)&Vt[buf][d][(g * 8) ^ sw];
            const bf16x8 vb1 = *(const bf16x8*)&Vt[buf][d][(32 + g * 8) ^ sw];
            if (dt == 0) {
                acc0 = __builtin_amdgcn_mfma_f32_16x16x32_bf16(pa0, vb0, acc0, 0, 0, 0);
                acc0 = __builtin_amdgcn_mfma_f32_16x16x32_bf16(pa1, vb1, acc0, 0, 0, 0);
            } else {
                acc1 = __builtin_amdgcn_mfma_f32_16x16x32_bf16(pa0, vb0, acc1, 0, 0, 0);
                acc1 = __builtin_amdgcn_mfma_f32_16x16x32_bf16(pa1, vb1, acc1, 0, 0, 0);
            }
        }
    }

    // ---- store unnormalized partial (C row = q' = g*4+r, col = d)
    const int task = (b * 8 + h) * 16 + qt * 4 + wid;
    const int pbase = (task * S + split) * 16;
    #pragma unroll
    for (int r = 0; r < 4; ++r) {
        accp[(size_t)(pbase + g * 4 + r) * 32 + q15]      = acc0[r];
        accp[(size_t)(pbase + g * 4 + r) * 32 + 16 + q15] = acc1[r];
    }
    if (lane < 16)
        mlp[pbase + lane] = make_float2(m_run, l_run);
}

// ---------------------------------------------------------------------------
// combine split partials.  1 wave per task (16 q x 32 d).
// ---------------------------------------------------------------------------
template<int S>
__global__ __launch_bounds__(256) void attn_combine(
    const float* __restrict__ accp, const float2* __restrict__ mlp,
    bf16* __restrict__ Ob)
{
    const int tid = threadIdx.x, lane = tid & 63, wid = tid >> 6;
    const int task = blockIdx.x * 4 + wid;
    const int d = lane & 31, rh = lane >> 5;
    const int b = task >> 7, h = (task >> 4) & 7, qg = task & 15;

    #pragma unroll
    for (int qi = 0; qi < 8; ++qi) {
        const int q = rh * 8 + qi;
        float ms[S], ls[S];
        float m_g = -1e30f;
        #pragma unroll
        for (int s = 0; s < S; ++s) {
            const float2 ml = mlp[(task * S + s) * 16 + q];
            ms[s] = ml.x; ls[s] = ml.y;
            m_g = fmaxf(m_g, ms[s]);
        }
        float l_g = 0.f, o = 0.f;
        #pragma unroll
        for (int s = 0; s < S; ++s) {
            const float f = exp2f(ms[s] - m_g);
            l_g += ls[s] * f;
            o += accp[(size_t)((task * S + s) * 16 + q) * 32 + d] * f;
        }
        const size_t row = (size_t)b * LQ_ + qg * 16 + q;
        Ob[row * D + h * HD + d] = (bf16)(o / l_g);
    }
}

// ---------------------------------------------------------------------------
// output projection (f32 out; residual+LN in ln_kernel)
// ---------------------------------------------------------------------------
__global__ __launch_bounds__(256) void out_proj_kernel(
    const bf16* __restrict__ a, const bf16* __restrict__ wb,
    const float* __restrict__ bias, float* __restrict__ outR)
{
    __shared__ bf16 As[128][72];
    __shared__ bf16 Bs[128][72];
    const int tid = threadIdx.x, lane = tid & 63, wid = tid >> 6;
    const int wm = wid >> 1, wn = wid & 1;
    const int nblk = blockIdx.x, mblk = blockIdx.y;

    f32x4 acc[4][4];
    #pragma unroll
    for (int i = 0; i < 4; ++i)
        #pragma unroll
        for (int j = 0; j < 4; ++j) acc[i][j] = (f32x4){0.f, 0.f, 0.f, 0.f};

    for (int kk = 0; kk < 4; ++kk) {
        const int d0 = kk * 64;
        #pragma unroll
        for (int i = 0; i < 4; ++i) {
            const int idx = i * 256 + tid;
            const int r = idx >> 3, c = (idx & 7) * 8;
            *(bf16x8*)&As[r][c] =
                *(const bf16x8*)&a[(size_t)(mblk * 128 + r) * D + d0 + c];
            *(bf16x8*)&Bs[r][c] =
                *(const bf16x8*)&wb[(size_t)(nblk * 128 + r) * D + d0 + c];
        }
        __syncthreads();
        #pragma unroll
        for (int h2 = 0; h2 < 2; ++h2) {
            const int ko = h2 * 32 + (lane >> 4) * 8;
            bf16x8 af[4], bfr[4];
            #pragma unroll
            for (int i = 0; i < 4; ++i)
                af[i] = *(const bf16x8*)&As[wm * 64 + i * 16 + (lane & 15)][ko];
            #pragma unroll
            for (int j = 0; j < 4; ++j)
                bfr[j] = *(const bf16x8*)&Bs[wn * 64 + j * 16 + (lane & 15)][ko];
            #pragma unroll
            for (int i = 0; i < 4; ++i)
                #pragma unroll
                for (int j = 0; j < 4; ++j)
                    acc[i][j] = __builtin_amdgcn_mfma_f32_16x16x32_bf16(
                        af[i], bfr[j], acc[i][j], 0, 0, 0);
        }
        __syncthreads();
    }

    #pragma unroll
    for (int i = 0; i < 4; ++i)
        #pragma unroll
        for (int j = 0; j < 4; ++j) {
            const int n_g = nblk * 128 + wn * 64 + j * 16 + (lane & 15);
            const float b = bias[n_g];
            #pragma unroll
            for (int r = 0; r < 4; ++r) {
                const size_t m_g = (size_t)mblk * 128 + wm * 64 + i * 16 + (lane >> 4) * 4 + r;
                outR[m_g * D + n_g] = acc[i][j][r] + b;
            }
        }
}

// ---------------------------------------------------------------------------
// residual + LayerNorm.  1 wave per 256-wide row, 4 rows/block.
// ---------------------------------------------------------------------------
__global__ __launch_bounds__(256) void ln_kernel(
    const float* __restrict__ Rb, const float* __restrict__ query,
    const float* __restrict__ lnw, const float* __restrict__ lnb,
    float* __restrict__ out)
{
    const int tid = threadIdx.x, lane = tid & 63, wid = tid >> 6;
    const size_t row = (size_t)blockIdx.x * 4 + wid;
    const float4 a = *(const float4*)&Rb[row * D + lane * 4];
    const float4 q = *(const float4*)&query[row * D + lane * 4];
    float4 r = make_float4(a.x + q.x, a.y + q.y, a.z + q.z, a.w + q.w);
    float s  = r.x + r.y + r.z + r.w;
    float sq = r.x * r.x + r.y * r.y + r.z * r.z + r.w * r.w;
    #pragma unroll
    for (int m = 1; m <= 32; m <<= 1) {
        s  += __shfl_xor(s,  m);
        sq += __shfl_xor(sq, m);
    }
    const float mean = s * (1.f / 256.f);
    const float var  = sq * (1.f / 256.f) - mean * mean;
    const float inv  = rsqrtf(var + 1e-5f);
    const float4 w = *(const float4*)&lnw[lane * 4];
    const float4 bb = *(const float4*)&lnb[lane * 4];
    float4 y;
    y.x = (r.x - mean) * inv * w.x + bb.x;
    y.y = (r.y - mean) * inv * w.y + bb.y;
    y.z = (r.z - mean) * inv * w.z + bb.z;
    y.w = (r.w - mean) * inv * w.w + bb.w;
    *(float4*)&out[row * D + lane * 4] = y;
}

// ---------------------------------------------------------------------------
extern "C" void kernel_launch(void* const* d_in, const int* in_sizes, int n_in,
                              void* d_out, int out_size, void* d_ws, size_t ws_size,
                              hipStream_t stream) {
    (void)in_sizes; (void)n_in; (void)out_size;
    const float* source    = (const float*)d_in[0];
    const float* query     = (const float*)d_in[1];
    const float* source_pe = (const float*)d_in[2];
    const float* query_pe  = (const float*)d_in[3];
    const float* in_proj_w = (const float*)d_in[4];
    const float* in_proj_b = (const float*)d_in[5];
    const float* out_w     = (const float*)d_in[6];
    const float* out_b     = (const float*)d_in[7];
    const float* ln_w      = (const float*)d_in[8];
    const float* ln_b      = (const float*)d_in[9];

    // workspace layout (total 56,098,816 B == last round's verified need)
    bf16* Wb  = (bf16*)d_ws;                  // 1024 x 256 bf16 (in_proj ++ out_w)
    bf16* Qb  = Wb + 1024 * 256;              // 2048 x 256
    bf16* Kb  = Qb + (size_t)MQ * D;          // 32768 x 256
    bf16* Vb  = Kb + (size_t)MS * D;          // 32768 x 256
    bf16* Ob  = Vb + (size_t)MS * D;          // 2048 x 256
    float* Rb = (float*)(Ob + (size_t)MQ * D);// 2048 x 256 f32
    bf16* QPb = (bf16*)(Rb + (size_t)MQ * D); // 2048 x 256 bf16 (later: mlp)
    bf16* Xb  = QPb + (size_t)MQ * D;         // 32768 x 256 bf16 (SPb/Sb, later: accp)
    float*  accp = (float*)Xb;
    float2* mlp  = (float2*)QPb;
    float* outp = (float*)d_out;

    // 1. SPb = bf16(source+pe), QPb, Wb
    prep1<<<dim3(2048), dim3(256), 0, stream>>>(
        source, source_pe, query, query_pe, in_proj_w, out_w, Xb, QPb, Wb);
    // 2. K = SPb @ Wk^T
    gemm_proj<<<dim3(2, 256), dim3(256), 0, stream>>>(
        Xb, Wb + 256 * D, in_proj_b + 256, Kb, 1.0f);
    // 3. Sb = bf16(source) (overwrites SPb)
    prep2<<<dim3(2048), dim3(256), 0, stream>>>(source, Xb);
    // 4. V = Sb @ Wv^T
    gemm_proj<<<dim3(2, 256), dim3(256), 0, stream>>>(
        Xb, Wb + 512 * D, in_proj_b + 512, Vb, 1.0f);
    // 5. Q = QPb @ Wq^T, scaled
    gemm_proj<<<dim3(2, 16), dim3(256), 0, stream>>>(
        QPb, Wb, in_proj_b, Qb, QSCALE);

    // 6/7. attention (accp overlays Xb, mlp overlays QPb - both dead by now)
    constexpr int S = 8;
    attn_kernel<S><<<dim3(256 * S), dim3(256), 0, stream>>>(Qb, Kb, Vb, accp, mlp);
    attn_combine<S><<<dim3(256), dim3(256), 0, stream>>>(accp, mlp, Ob);

    // 8/9. out projection + residual/LN
    out_proj_kernel<<<dim3(2, 16), dim3(256), 0, stream>>>(
        Ob, Wb + 768 * 256, out_b, Rb);
    ln_kernel<<<dim3(512), dim3(256), 0, stream>>>(Rb, query, ln_w, ln_b, outp);
}

// Round 4
// 113.085 us; speedup vs baseline: 1.2500x; 1.2500x over previous
//
#include <hip/hip_runtime.h>
#include <hip/hip_bf16.h>

typedef __bf16 bf16;
typedef __bf16 bf16x4 __attribute__((ext_vector_type(4)));
typedef __bf16 bf16x8 __attribute__((ext_vector_type(8)));
typedef float f32x4 __attribute__((ext_vector_type(4)));

#define D 256          // embed dim
#define NHEAD 8
#define HD 32          // head dim
#define NB_ 8
#define LQ_ 256
#define LS_ 4096
#define MQ (NB_ * LQ_)   // 2048
#define MS (NB_ * LS_)   // 32768

// softmax scale folded into Q projection: hd^-0.5 * log2(e)
#define QSCALE 0.25500527f

// ---------------------------------------------------------------------------
// prep: SPb = bf16(source+pe); [Sb = bf16(source)]; QPb = bf16(query+qpe);
//       Wb = bf16(in_proj_w ++ out_w)
// ---------------------------------------------------------------------------
__global__ __launch_bounds__(256) void prep(
    const float* __restrict__ source, const float* __restrict__ source_pe,
    const float* __restrict__ query, const float* __restrict__ query_pe,
    const float* __restrict__ w_in, const float* __restrict__ w_out,
    bf16* __restrict__ SPb, bf16* __restrict__ Sb, bf16* __restrict__ QPb,
    bf16* __restrict__ Wb, int write_sb)
{
    const int NS4 = MS * D / 4;                  // 2097152
    const int NQ4 = MQ * D / 4;                  // 131072
    const int NW4 = (768 * 256 + 256 * 256) / 4; // 65536
    const int total = NS4 + NQ4 + NW4;
    for (int i = blockIdx.x * 256 + threadIdx.x; i < total; i += gridDim.x * 256) {
        if (i < NS4) {
            const float4 s = ((const float4*)source)[i];
            const float4 p = ((const float4*)source_pe)[i];
            bf16x4 osp;
            osp[0] = (bf16)(s.x + p.x); osp[1] = (bf16)(s.y + p.y);
            osp[2] = (bf16)(s.z + p.z); osp[3] = (bf16)(s.w + p.w);
            ((bf16x4*)SPb)[i] = osp;
            if (write_sb) {
                bf16x4 os;
                os[0] = (bf16)s.x; os[1] = (bf16)s.y;
                os[2] = (bf16)s.z; os[3] = (bf16)s.w;
                ((bf16x4*)Sb)[i] = os;
            }
        } else if (i < NS4 + NQ4) {
            const int j = i - NS4;
            const float4 s = ((const float4*)query)[j];
            const float4 p = ((const float4*)query_pe)[j];
            bf16x4 o;
            o[0] = (bf16)(s.x + p.x); o[1] = (bf16)(s.y + p.y);
            o[2] = (bf16)(s.z + p.z); o[3] = (bf16)(s.w + p.w);
            ((bf16x4*)QPb)[j] = o;
        } else {
            const int j = i - NS4 - NQ4;
            const float4 v = (j < 49152) ? ((const float4*)w_in)[j]
                                         : ((const float4*)w_out)[j - 49152];
            bf16x4 o;
            o[0] = (bf16)v.x; o[1] = (bf16)v.y; o[2] = (bf16)v.z; o[3] = (bf16)v.w;
            ((bf16x4*)Wb)[j] = o;
        }
    }
}

// prep2 (fallback only): Sb = bf16(source)
__global__ __launch_bounds__(256) void prep2(
    const float* __restrict__ source, bf16* __restrict__ Sb)
{
    const int NS4 = MS * D / 4;
    for (int i = blockIdx.x * 256 + threadIdx.x; i < NS4; i += gridDim.x * 256) {
        const float4 s = ((const float4*)source)[i];
        bf16x4 o;
        o[0] = (bf16)s.x; o[1] = (bf16)s.y; o[2] = (bf16)s.z; o[3] = (bf16)s.w;
        ((bf16x4*)Sb)[i] = o;
    }
}

// ---------------------------------------------------------------------------
// unified projection GEMM (K, V, Q in one dispatch).
// by = blockIdx.x + by_off:
//   mblk<256 : by 0,1 -> K from SPb (nblk=by&1); by 2,3 -> V from Sb
//   mblk>=256: by 0,1 -> Q from QPb (mblk-256);  by 2,3 -> exit
// ---------------------------------------------------------------------------
__global__ __launch_bounds__(256) void gemm_proj_all(
    const bf16* __restrict__ SPb, const bf16* __restrict__ Sb,
    const bf16* __restrict__ QPb, const bf16* __restrict__ Wb,
    const float* __restrict__ in_proj_b,
    bf16* __restrict__ Kb, bf16* __restrict__ Vb, bf16* __restrict__ Qb,
    int by_off)
{
    __shared__ bf16 As[128][72];
    __shared__ bf16 Bs[128][72];
    const int tid = threadIdx.x, lane = tid & 63, wid = tid >> 6;
    const int wm = wid >> 1, wn = wid & 1;
    const int by = blockIdx.x + by_off;
    const int mb = blockIdx.y;
    const int nblk = by & 1;

    const bf16* A; const bf16* W; const float* bias; bf16* out;
    float scale; size_t arow0;
    if (mb < 256) {
        arow0 = (size_t)mb * 128;
        if (by < 2) { A = SPb; W = Wb + 256 * D; bias = in_proj_b + 256; out = Kb; scale = 1.0f; }
        else        { A = Sb;  W = Wb + 512 * D; bias = in_proj_b + 512; out = Vb; scale = 1.0f; }
    } else {
        if (by >= 2) return;
        arow0 = (size_t)(mb - 256) * 128;
        A = QPb; W = Wb; bias = in_proj_b; out = Qb; scale = QSCALE;
    }

    f32x4 acc[4][4];
    #pragma unroll
    for (int i = 0; i < 4; ++i)
        #pragma unroll
        for (int j = 0; j < 4; ++j) acc[i][j] = (f32x4){0.f, 0.f, 0.f, 0.f};

    const int brow0 = nblk * 128;

    for (int kk = 0; kk < 4; ++kk) {
        const int d0 = kk * 64;
        #pragma unroll
        for (int i = 0; i < 4; ++i) {
            const int idx = i * 256 + tid;
            const int r = idx >> 3, c = (idx & 7) * 8;
            *(bf16x8*)&As[r][c] = *(const bf16x8*)&A[(arow0 + r) * D + d0 + c];
            *(bf16x8*)&Bs[r][c] = *(const bf16x8*)&W[(size_t)(brow0 + r) * D + d0 + c];
        }
        __syncthreads();
        #pragma unroll
        for (int h2 = 0; h2 < 2; ++h2) {
            const int ko = h2 * 32 + (lane >> 4) * 8;
            bf16x8 af[4], bfr[4];
            #pragma unroll
            for (int i = 0; i < 4; ++i)
                af[i] = *(const bf16x8*)&As[wm * 64 + i * 16 + (lane & 15)][ko];
            #pragma unroll
            for (int j = 0; j < 4; ++j)
                bfr[j] = *(const bf16x8*)&Bs[wn * 64 + j * 16 + (lane & 15)][ko];
            #pragma unroll
            for (int i = 0; i < 4; ++i)
                #pragma unroll
                for (int j = 0; j < 4; ++j)
                    acc[i][j] = __builtin_amdgcn_mfma_f32_16x16x32_bf16(
                        af[i], bfr[j], acc[i][j], 0, 0, 0);
        }
        __syncthreads();
    }

    #pragma unroll
    for (int i = 0; i < 4; ++i)
        #pragma unroll
        for (int j = 0; j < 4; ++j) {
            const int n_g = brow0 + wn * 64 + j * 16 + (lane & 15);
            const float b = bias[n_g];
            #pragma unroll
            for (int r = 0; r < 4; ++r) {
                const size_t m_g = arow0 + wm * 64 + i * 16 + (lane >> 4) * 4 + r;
                out[m_g * D + n_g] = (bf16)((acc[i][j][r] + b) * scale);
            }
        }
}

// ---------------------------------------------------------------------------
// split-KV flash attention, fixed-offset softmax (no online max).
// s = K·Q - 8 (C-init), p = exp2(s); combine is a plain sum.
// accp layout: [task][split][lane][8] -> wave writes contiguous 2KB.
// ---------------------------------------------------------------------------
template<int S>
__global__ __launch_bounds__(256, 8) void attn_kernel(
    const bf16* __restrict__ Qb, const bf16* __restrict__ Kb,
    const bf16* __restrict__ Vb,
    float* __restrict__ accp, float* __restrict__ lp)
{
    __shared__ bf16 Vt[2][32][72];   // V^T chunk, double buffered, XOR-swizzled

    const int tid = threadIdx.x, lane = tid & 63, wid = tid >> 6;
    const int q15 = lane & 15, g = lane >> 4;
    const int bid = blockIdx.x;
    const int h = bid & 7;
    const int inner = bid >> 3;
    const int b = inner / (S * 4);
    const int rem = inner % (S * 4);
    const int split = rem >> 2, qt = rem & 3;

    const int q0 = b * LQ_ + qt * 64 + wid * 16;
    const bf16x8 qf = *(const bf16x8*)&Qb[(size_t)(q0 + q15) * D + h * HD + g * 8];

    const size_t kvbase = (size_t)b * LS_;
    const int kv0 = split * (LS_ / S);
    const f32x4 minit = (f32x4){-8.f, -8.f, -8.f, -8.f};
    const int rbase = 8 * (q15 >> 2) + (q15 & 3);   // kf row permutation base

    float l_run = 0.f;
    f32x4 acc0 = (f32x4){0.f, 0.f, 0.f, 0.f};
    f32x4 acc1 = (f32x4){0.f, 0.f, 0.f, 0.f};

    const int vrow = tid >> 2, vc = (tid & 3) * 8;

    for (int kc = 0; kc < LS_ / S / 64; ++kc) {
        const int k0 = kv0 + kc * 64;
        const int buf = kc & 1;

        // ---- stage V^T chunk (swizzled: kv' = kv ^ ((d>>3)<<4))
        const bf16x8 vv = *(const bf16x8*)&Vb[(kvbase + k0 + vrow) * D + h * HD + vc];
        #pragma unroll
        for (int j = 0; j < 8; ++j) {
            const int d = vc + j;
            Vt[buf][d][vrow ^ ((d >> 3) << 4)] = vv[j];
        }
        __syncthreads();

        // ---- S^T = K Q^T - 8: lane holds 16 kv scores for q = q0 + q15
        f32x4 s[4];
        #pragma unroll
        for (int t = 0; t < 4; ++t) {
            const int row = 32 * (t >> 1) + 4 * (t & 1) + rbase;
            const bf16x8 kf = *(const bf16x8*)
                &Kb[(kvbase + k0 + row) * D + h * HD + g * 8];
            s[t] = __builtin_amdgcn_mfma_f32_16x16x32_bf16(kf, qf, minit, 0, 0, 0);
        }

        // ---- p = exp2(s); accumulate l; pack P fragments (lane-local)
        bf16x8 pa0, pa1;
        #pragma unroll
        for (int r = 0; r < 4; ++r) {
            const float p0 = exp2f(s[0][r]);
            const float p1 = exp2f(s[1][r]);
            const float p2 = exp2f(s[2][r]);
            const float p3 = exp2f(s[3][r]);
            l_run += (p0 + p1) + (p2 + p3);
            pa0[r]     = (bf16)p0;
            pa0[4 + r] = (bf16)p1;
            pa1[r]     = (bf16)p2;
            pa1[4 + r] = (bf16)p3;
        }

        // ---- O += P V
        #pragma unroll
        for (int dt = 0; dt < 2; ++dt) {
            const int d = dt * 16 + q15;
            const int sw = (d >> 3) << 4;
            const bf16x8 vb0 = *(const bf16x8*)&Vt[buf][d][(g * 8) ^ sw];
            const bf16x8 vb1 = *(const bf16x8*)&Vt[buf][d][(32 + g * 8) ^ sw];
            if (dt == 0) {
                acc0 = __builtin_amdgcn_mfma_f32_16x16x32_bf16(pa0, vb0, acc0, 0, 0, 0);
                acc0 = __builtin_amdgcn_mfma_f32_16x16x32_bf16(pa1, vb1, acc0, 0, 0, 0);
            } else {
                acc1 = __builtin_amdgcn_mfma_f32_16x16x32_bf16(pa0, vb0, acc1, 0, 0, 0);
                acc1 = __builtin_amdgcn_mfma_f32_16x16x32_bf16(pa1, vb1, acc1, 0, 0, 0);
            }
        }
    }

    // ---- one final l reduce across the 4 lane-groups (same q15)
    l_run += __shfl_xor(l_run, 16);
    l_run += __shfl_xor(l_run, 32);

    // ---- store partials: wave-contiguous 2KB block
    const int task = (b * 8 + h) * 16 + qt * 4 + wid;
    const size_t base = ((size_t)(task * S + split) * 64 + lane) * 8;
    *(f32x4*)&accp[base]     = acc0;
    *(f32x4*)&accp[base + 4] = acc1;
    if (lane < 16)
        lp[(task * S + split) * 16 + lane] = l_run;
}

// ---------------------------------------------------------------------------
// combine split partials: plain sums.  1 wave per task.
// value j of lane (g,q15): j<4 -> (q=g*4+j, d=q15); j>=4 -> d=16+q15.
// ---------------------------------------------------------------------------
template<int S>
__global__ __launch_bounds__(256) void attn_combine(
    const float* __restrict__ accp, const float* __restrict__ lp,
    bf16* __restrict__ Ob)
{
    const int tid = threadIdx.x, lane = tid & 63, wid = tid >> 6;
    const int task = blockIdx.x * 4 + wid;
    const int g = lane >> 4, q15 = lane & 15;

    f32x4 o0 = (f32x4){0.f, 0.f, 0.f, 0.f};
    f32x4 o1 = (f32x4){0.f, 0.f, 0.f, 0.f};
    float ll = 0.f;
    #pragma unroll
    for (int s = 0; s < S; ++s) {
        const size_t base = ((size_t)(task * S + s) * 64 + lane) * 8;
        o0 += *(const f32x4*)&accp[base];
        o1 += *(const f32x4*)&accp[base + 4];
        if (lane < 16) ll += lp[(task * S + s) * 16 + lane];
    }

    const int b = task >> 7, h = (task >> 4) & 7, qg = task & 15;
    #pragma unroll
    for (int r = 0; r < 4; ++r) {
        const float inv = 1.f / __shfl(ll, g * 4 + r);
        const size_t row = (size_t)b * LQ_ + qg * 16 + g * 4 + r;
        Ob[row * D + h * HD + q15]      = (bf16)(o0[r] * inv);
        Ob[row * D + h * HD + 16 + q15] = (bf16)(o1[r] * inv);
    }
}

// ---------------------------------------------------------------------------
// fused output projection + bias + residual + LayerNorm.
// grid 16 blocks; block = 128 rows x 256 cols; 4 waves (wm,wn), acc[4][8].
// ---------------------------------------------------------------------------
__global__ __launch_bounds__(256) void out_ln_kernel(
    const bf16* __restrict__ Ob, const bf16* __restrict__ Wout,
    const float* __restrict__ out_b, const float* __restrict__ query,
    const float* __restrict__ lnw, const float* __restrict__ lnb,
    float* __restrict__ out)
{
    __shared__ bf16 As[128][72];
    __shared__ bf16 Bs[256][72];
    __shared__ float red[2][128][2];
    const int tid = threadIdx.x, lane = tid & 63, wid = tid >> 6;
    const int wm = wid >> 1, wn = wid & 1;
    const int g = lane >> 4, q15 = lane & 15;
    const int mblk = blockIdx.x;

    f32x4 acc[4][8];
    #pragma unroll
    for (int i = 0; i < 4; ++i)
        #pragma unroll
        for (int j = 0; j < 8; ++j) acc[i][j] = (f32x4){0.f, 0.f, 0.f, 0.f};

    for (int kk = 0; kk < 4; ++kk) {
        const int d0 = kk * 64;
        #pragma unroll
        for (int i = 0; i < 4; ++i) {
            const int idx = i * 256 + tid;
            const int r = idx >> 3, c = (idx & 7) * 8;
            *(bf16x8*)&As[r][c] =
                *(const bf16x8*)&Ob[(size_t)(mblk * 128 + r) * D + d0 + c];
        }
        #pragma unroll
        for (int i = 0; i < 8; ++i) {
            const int idx = i * 256 + tid;
            const int r = idx >> 3, c = (idx & 7) * 8;
            *(bf16x8*)&Bs[r][c] = *(const bf16x8*)&Wout[(size_t)r * D + d0 + c];
        }
        __syncthreads();
        #pragma unroll
        for (int h2 = 0; h2 < 2; ++h2) {
            const int ko = h2 * 32 + g * 8;
            bf16x8 af[4], bfr[8];
            #pragma unroll
            for (int i = 0; i < 4; ++i)
                af[i] = *(const bf16x8*)&As[wm * 64 + i * 16 + q15][ko];
            #pragma unroll
            for (int j = 0; j < 8; ++j)
                bfr[j] = *(const bf16x8*)&Bs[wn * 128 + j * 16 + q15][ko];
            #pragma unroll
            for (int i = 0; i < 4; ++i)
                #pragma unroll
                for (int j = 0; j < 8; ++j)
                    acc[i][j] = __builtin_amdgcn_mfma_f32_16x16x32_bf16(
                        af[i], bfr[j], acc[i][j], 0, 0, 0);
        }
        __syncthreads();
    }

    // per-lane column constants
    float bl[8], lw[8], lbv[8];
    #pragma unroll
    for (int j = 0; j < 8; ++j) {
        const int n = wn * 128 + j * 16 + q15;
        bl[j] = out_b[n]; lw[j] = lnw[n]; lbv[j] = lnb[n];
    }

    // add bias + residual, compute per-row partial sums, reduce, publish
    #pragma unroll
    for (int i = 0; i < 4; ++i) {
        #pragma unroll
        for (int r = 0; r < 4; ++r) {
            const size_t m = (size_t)mblk * 128 + wm * 64 + i * 16 + g * 4 + r;
            float s = 0.f, sq = 0.f;
            #pragma unroll
            for (int j = 0; j < 8; ++j) {
                const float v = acc[i][j][r] + bl[j] + query[m * D + wn * 128 + j * 16 + q15];
                acc[i][j][r] = v;
                s += v; sq += v * v;
            }
            s += __shfl_xor(s, 1);  sq += __shfl_xor(sq, 1);
            s += __shfl_xor(s, 2);  sq += __shfl_xor(sq, 2);
            s += __shfl_xor(s, 4);  sq += __shfl_xor(sq, 4);
            s += __shfl_xor(s, 8);  sq += __shfl_xor(sq, 8);
            if (q15 == i * 4 + r) {
                red[wn][wm * 64 + i * 16 + g * 4 + r][0] = s;
                red[wn][wm * 64 + i * 16 + g * 4 + r][1] = sq;
            }
        }
    }
    __syncthreads();

    // normalize + store
    #pragma unroll
    for (int i = 0; i < 4; ++i)
        #pragma unroll
        for (int r = 0; r < 4; ++r) {
            const int row = wm * 64 + i * 16 + g * 4 + r;
            const float s  = red[0][row][0] + red[1][row][0];
            const float sq = red[0][row][1] + red[1][row][1];
            const float mean = s * (1.f / 256.f);
            const float var  = sq * (1.f / 256.f) - mean * mean;
            const float inv  = rsqrtf(var + 1e-5f);
            const size_t m = (size_t)mblk * 128 + row;
            #pragma unroll
            for (int j = 0; j < 8; ++j)
                out[m * D + wn * 128 + j * 16 + q15] =
                    (acc[i][j][r] - mean) * inv * lw[j] + lbv[j];
        }
}

// ---------------------------------------------------------------------------
extern "C" void kernel_launch(void* const* d_in, const int* in_sizes, int n_in,
                              void* d_out, int out_size, void* d_ws, size_t ws_size,
                              hipStream_t stream) {
    (void)in_sizes; (void)n_in; (void)out_size;
    const float* source    = (const float*)d_in[0];
    const float* query     = (const float*)d_in[1];
    const float* source_pe = (const float*)d_in[2];
    const float* query_pe  = (const float*)d_in[3];
    const float* in_proj_w = (const float*)d_in[4];
    const float* in_proj_b = (const float*)d_in[5];
    const float* out_w     = (const float*)d_in[6];
    const float* out_b     = (const float*)d_in[7];
    const float* ln_w      = (const float*)d_in[8];
    const float* ln_b      = (const float*)d_in[9];

    constexpr int S = 8;
    // workspace layout
    bf16* Wb  = (bf16*)d_ws;                   //  0.5 MB (in_proj ++ out_w)
    bf16* Qb  = Wb + 1024 * 256;               //  1 MB
    bf16* Kb  = Qb + (size_t)MQ * D;           // 16.78 MB
    bf16* Vb  = Kb + (size_t)MS * D;           // 16.78 MB
    bf16* Ob  = Vb + (size_t)MS * D;           //  1 MB
    bf16* QPb = Ob + (size_t)MQ * D;           //  1 MB   (later: lp, 0.5 MB)
    bf16* SPb = QPb + (size_t)MQ * D;          // 16.78 MB (later: accp, exact fit)
    bf16* Sb  = SPb + (size_t)MS * D;          // 16.78 MB (fast path only)
    float* accp = (float*)SPb;
    float* lp   = (float*)QPb;
    float* outp = (float*)d_out;

    const size_t need_fast = (size_t)((char*)(Sb + (size_t)MS * D) - (char*)d_ws);
    const bool fast = (ws_size >= need_fast);

    if (fast) {
        prep<<<dim3(2048), dim3(256), 0, stream>>>(
            source, source_pe, query, query_pe, in_proj_w, out_w,
            SPb, Sb, QPb, Wb, 1);
        gemm_proj_all<<<dim3(4, 272), dim3(256), 0, stream>>>(
            SPb, Sb, QPb, Wb, in_proj_b, Kb, Vb, Qb, 0);
    } else {
        prep<<<dim3(2048), dim3(256), 0, stream>>>(
            source, source_pe, query, query_pe, in_proj_w, out_w,
            SPb, SPb, QPb, Wb, 0);
        // K + Q
        gemm_proj_all<<<dim3(2, 272), dim3(256), 0, stream>>>(
            SPb, SPb, QPb, Wb, in_proj_b, Kb, Vb, Qb, 0);
        // re-fill region with bf16(source), then V
        prep2<<<dim3(2048), dim3(256), 0, stream>>>(source, SPb);
        gemm_proj_all<<<dim3(2, 256), dim3(256), 0, stream>>>(
            SPb, SPb, QPb, Wb, in_proj_b, Kb, Vb, Qb, 2);
    }

    attn_kernel<S><<<dim3(256 * S), dim3(256), 0, stream>>>(Qb, Kb, Vb, accp, lp);
    attn_combine<S><<<dim3(256), dim3(256), 0, stream>>>(accp, lp, Ob);
    out_ln_kernel<<<dim3(16), dim3(256), 0, stream>>>(
        Ob, Wb + 768 * 256, out_b, query, ln_w, ln_b, outp);
}